// Round 1
// baseline (212.209 us; speedup 1.0000x reference)
//
#include <hip/hip_runtime.h>
#include <hip/hip_bf16.h>

#define HH    48
#define WW    64
#define CC    256
#define ND    21
#define OUTD  441
#define PITCH 264        // LDS row pitch in bf16 elems (16B-aligned rows, 4-bank rotate)
#define SROWS 32         // j' rows per parity

typedef __bf16 v8bf16 __attribute__((ext_vector_type(8)));
typedef float  v4f    __attribute__((ext_vector_type(4)));

// out[b,h,w, tj*21+ti] = (1/256) * sum_c A[b,h,w,c] * Bpad[b, h+2tj-20, w+2ti-20, c]
// h-parity and w-parity both decompose the problem. Block owns (b, w-parity p,
// h-triple {h0,h0+2,h0+4}, i-chunk ck): A fragments in registers (1 h-row per wave),
// loop over a CHUNK of shared hb rows; stage B[hb] parity-p cols to LDS
// (double-buffered, register-prefetched, one barrier/iter). Each staged row serves
// up to 3 (h,tj) pairs. The i-range split (ck) doubles the grid to 1024 blocks
// -> 4 blocks/CU (was 2), lifting the 37.5% occupancy cap that left the kernel
// latency-bound at 2.5 TB/s.
__global__ __launch_bounds__(384)
void corr_mfma_kernel(const float* __restrict__ A, const float* __restrict__ B,
                      float* __restrict__ out) {
    __shared__ __bf16 Blds[2][SROWS * PITCH];   // 2 x 16,896 B

    const int blk  = blockIdx.x;
    const int b    = blk >> 6;        // 16 images, 64 blocks/image
    const int rem  = blk & 63;
    const int ck   = rem & 1;         // i-range chunk (0 = low half, 1 = high half)
    const int p    = (rem >> 1) & 1;  // w parity
    const int hpar = (rem >> 2) & 1;  // h parity
    const int trip = rem >> 3;        // [0,8)
    const int h0   = 6 * trip + hpar; // rows h0, h0+2, h0+4

    const int tid  = threadIdx.x;
    const int lane = tid & 63;
    const int wave = tid >> 6;        // [0,6)
    const int mt   = wave & 1;        // w'-tile
    const int hr   = wave >> 1;       // [0,3): which h-row
    const int n    = lane & 15;
    const int quad = lane >> 4;

    const int h = h0 + 2 * hr;

    // hb = h0 - 20 + 2i ; full i range keeping hb in [0,48)
    const int i_lo_f = (h0 >= 21) ? 0 : ((21 - h0) >> 1);
    const int i_hi_f = min(22, (67 - h0) >> 1);
    const int i_mid  = (i_lo_f + i_hi_f + 1) >> 1;
    const int i_lo   = ck ? i_mid : i_lo_f;          // chunk ranges are contiguous,
    const int i_hi   = ck ? i_hi_f : (i_mid - 1);    // disjoint, both non-empty (>=6)

    // ---- zero-fill invalid-tj entries for the 3 rows (parity-p w columns only) ----
    // chunk 0 owns the low-invalid tj ([0, i_lo_f-r-1]), chunk 1 the high-invalid
    // ([i_hi_f-r+1, 20]); disjoint union == the old invalid set.
    for (int r = 0; r < 3; ++r) {
        int hrow = h0 + 2 * r;
        int z_lo, z_hi;
        if (ck == 0) { z_lo = 0;                      z_hi = min(20, i_lo_f - r - 1); }
        else         { z_lo = max(0, i_hi_f - r + 1); z_hi = 20; }
        float* outr = out + (size_t)(b * HH + hrow) * WW * OUTD;
        for (int tj = z_lo; tj <= z_hi; ++tj) {
            for (int idx = tid; idx < 32 * ND; idx += 384) {
                int wp = idx / ND, ti = idx - wp * ND;
                int w  = (wp << 1) + p;
                outr[(size_t)w * OUTD + tj * ND + ti] = 0.f;
            }
        }
    }

    // ---- A fragments (loop-invariant, loaded once) ----
    v8bf16 afrag[8];
    {
        int w_a = ((mt * 16 + n) << 1) + p;
        const float* arow = A + ((size_t)(b * HH + h) * WW + w_a) * CC;
        #pragma unroll
        for (int kc = 0; kc < 8; ++kc) {
            int c0 = kc * 32 + quad * 8;
            float4 f0 = *(const float4*)(arow + c0);
            float4 f1 = *(const float4*)(arow + c0 + 4);
            v8bf16 af;
            af[0] = (__bf16)f0.x; af[1] = (__bf16)f0.y; af[2] = (__bf16)f0.z; af[3] = (__bf16)f0.w;
            af[4] = (__bf16)f1.x; af[5] = (__bf16)f1.y; af[6] = (__bf16)f1.z; af[7] = (__bf16)f1.w;
            afrag[kc] = af;
        }
    }

    // ---- staging: 32 j'-rows x 64 float4-chunks = 2048 chunks over 384 threads ----
    const float* bimg = B + (size_t)(b * HH) * WW * CC + p * CC;  // +p: j = 2j'+p
    float4 pf[6];
    auto load_pf = [&](int hb) {
        const float* brow = bimg + (size_t)hb * WW * CC;
        #pragma unroll
        for (int it = 0; it < 6; ++it) {
            int idx = it * 384 + tid;
            if (idx < 2048)
                pf[it] = *(const float4*)(brow + (idx >> 6) * 2 * CC + ((idx & 63) << 2));
        }
    };
    auto store_lds = [&](int buf) {
        #pragma unroll
        for (int it = 0; it < 6; ++it) {
            int idx = it * 384 + tid;
            if (idx < 2048) {
                __bf16* dst = &Blds[buf][(idx >> 6) * PITCH + ((idx & 63) << 2)];
                dst[0] = (__bf16)pf[it].x; dst[1] = (__bf16)pf[it].y;
                dst[2] = (__bf16)pf[it].z; dst[3] = (__bf16)pf[it].w;
            }
        }
    };

    load_pf(h0 - 20 + 2 * i_lo);
    store_lds(0);
    int cur = 0;

    float* outr = out + (size_t)(b * HH + h) * WW * OUTD;

    for (int i = i_lo; i <= i_hi; ++i) {
        if (i < i_hi) load_pf(h0 - 20 + 2 * (i + 1));   // prefetch next hb (in flight)
        __syncthreads();   // buf[cur] writes visible; prior readers of buf[cur^1] done

        const int tj = i - hr;
        if ((unsigned)tj <= 20u) {
            const __bf16* bbase = &Blds[cur][n * PITCH + quad * 8];
            v4f acc0 = {0.f, 0.f, 0.f, 0.f};
            v4f acc1 = acc0;
            #pragma unroll
            for (int kc = 0; kc < 8; ++kc) {
                v8bf16 bf0 = *(const v8bf16*)(bbase + kc * 32);                // j' = n
                v8bf16 bf1 = *(const v8bf16*)(bbase + 16 * PITCH + kc * 32);   // j' = 16+n
                acc0 = __builtin_amdgcn_mfma_f32_16x16x32_bf16(afrag[kc], bf0, acc0, 0, 0, 0);
                acc1 = __builtin_amdgcn_mfma_f32_16x16x32_bf16(afrag[kc], bf1, acc1, 0, 0, 0);
            }
            // epilogue: D col = n (-> j'), row = quad*4 + r (-> w' within tile)
            #pragma unroll
            for (int r = 0; r < 4; ++r) {
                int wp = mt * 16 + quad * 4 + r;
                int w  = (wp << 1) + p;
                float* orow = outr + (size_t)w * OUTD + tj * ND;
                int ti0 = 10 + n - wp;
                if ((unsigned)ti0 < 21u) orow[ti0] = acc0[r] * (1.f / 256.f);
                int ti1 = 26 + n - wp;
                if ((unsigned)ti1 < 21u) orow[ti1] = acc1[r] * (1.f / 256.f);
                // out-of-image j => exact zeros
                if (n < 10 - wp)  orow[n]      = 0.f;
                if (n <= wp - 22) orow[20 - n] = 0.f;
            }
        }

        if (i < i_hi) store_lds(cur ^ 1);   // consume pf; other buffer, no race
        cur ^= 1;
    }
}

extern "C" void kernel_launch(void* const* d_in, const int* in_sizes, int n_in,
                              void* d_out, int out_size, void* d_ws, size_t ws_size,
                              hipStream_t stream) {
    const float* A = (const float*)d_in[0];
    const float* B = (const float*)d_in[1];
    float* out = (float*)d_out;
    dim3 grid(16 * 64);
    dim3 block(384);
    corr_mfma_kernel<<<grid, block, 0, stream>>>(A, B, out);
}

// Round 2
// 206.656 us; speedup vs baseline: 1.0269x; 1.0269x over previous
//
#include <hip/hip_runtime.h>
#include <hip/hip_bf16.h>

#define HH    48
#define WW    64
#define CC    256
#define ND    21
#define OUTD  441
#define PITCH 264        // LDS row pitch in bf16 elems (16B-aligned rows, 4-bank rotate)
#define SROWS 32         // j' rows per parity

typedef __bf16 v8bf16 __attribute__((ext_vector_type(8)));
typedef __bf16 v4bf16 __attribute__((ext_vector_type(4)));
typedef float  v4f    __attribute__((ext_vector_type(4)));

// out[b,h,w, tj*21+ti] = (1/256) * sum_c A[b,h,w,c] * Bpad[b, h+2tj-20, w+2ti-20, c]
// A staged B row hb serves ANY same-parity h with tj=(hb-h+20)/2 in [0,20].
// Block owns (b, w-parity p, 6 h-rows {h0..h0+10}, i-chunk ck). 6 waves =
// (mt w-tile x h-pair): each wave holds A fragments for TWO h-rows and issues
// 4 MFMA chains per LDS fragment pair -> each staged row now feeds 6 h-rows
// (was 3), cutting staged-row count 2.4x and LDS-read redundancy 2x. Round-1
// showed the kernel is pipe-bound on per-staged-row machinery (2x grid -> +-0%),
// so total-staging reduction, not occupancy, is the lever.
__global__ __launch_bounds__(384)
void corr_mfma_kernel(const float* __restrict__ A, const float* __restrict__ B,
                      float* __restrict__ out) {
    __shared__ __bf16 Blds[2][SROWS * PITCH];   // 2 x 16,896 B

    const int blk  = blockIdx.x;
    const int b    = blk >> 5;        // 16 images, 32 blocks/image
    const int rem  = blk & 31;
    const int ck   = rem & 1;         // i-range chunk (0 = low half, 1 = high half)
    const int p    = (rem >> 1) & 1;  // w parity
    const int hpar = (rem >> 2) & 1;  // h parity
    const int grp  = rem >> 3;        // [0,4): group of 6 same-parity rows
    const int h0   = hpar + 12 * grp; // block rows: h0 + 2r, r in [0,6)

    const int tid  = threadIdx.x;
    const int lane = tid & 63;
    const int wave = tid >> 6;        // [0,6)
    const int mt   = wave & 1;        // w'-tile
    const int hg   = wave >> 1;       // [0,3): h-pair; wave rows r = 2hg, 2hg+1
    const int n    = lane & 15;
    const int quad = lane >> 4;

    // staged rows: hb = h0 - 20 + 2i, i in [i_lo_f, i_hi_f]
    // row r (h = h0+2r) consumes staged row i = tj + r.
    const int i_lo_f = (h0 >= 20) ? 0 : ((21 - h0) >> 1);
    const int i_hi_f = min(25, (67 - h0) >> 1);
    const int i_mid  = (i_lo_f + i_hi_f + 1) >> 1;
    const int i_lo   = ck ? i_mid : i_lo_f;          // contiguous, disjoint,
    const int i_hi   = ck ? i_hi_f : (i_mid - 1);    // both non-empty (>=7)

    // ---- staging helpers: 32 j'-rows x 64 float4-chunks = 2048 over 384 thr ----
    const float* bimg = B + (size_t)(b * HH) * WW * CC + p * CC;  // +p: j = 2j'+p
    float4 pf[6];
    auto load_pf = [&](int hb) {
        const float* brow = bimg + (size_t)hb * WW * CC;
        #pragma unroll
        for (int it = 0; it < 6; ++it) {
            int idx = it * 384 + tid;
            if (idx < 2048)
                pf[it] = *(const float4*)(brow + (idx >> 6) * 2 * CC + ((idx & 63) << 2));
        }
    };
    auto store_lds = [&](int buf) {
        #pragma unroll
        for (int it = 0; it < 6; ++it) {
            int idx = it * 384 + tid;
            if (idx < 2048) {
                v4bf16 t;
                t[0] = (__bf16)pf[it].x; t[1] = (__bf16)pf[it].y;
                t[2] = (__bf16)pf[it].z; t[3] = (__bf16)pf[it].w;
                *(v4bf16*)&Blds[buf][(idx >> 6) * PITCH + ((idx & 63) << 2)] = t;
            }
        }
    };

    load_pf(h0 - 20 + 2 * i_lo);   // issue early; completes under zero-fill/A-loads

    // ---- zero-fill invalid-tj entries for the 6 rows (parity-p w cols only) ----
    // ck0 owns invalid-low tj [0, i_lo_f-r-1]; ck1 invalid-high [i_hi_f-r+1, 20].
    for (int r = 0; r < 6; ++r) {
        int z_lo, z_hi;
        if (ck == 0) { z_lo = 0;                      z_hi = min(20, i_lo_f - r - 1); }
        else         { z_lo = max(0, i_hi_f - r + 1); z_hi = 20; }
        if (z_lo > z_hi) continue;
        float* outr = out + (size_t)(b * HH + h0 + 2 * r) * WW * OUTD;
        for (int tj = z_lo; tj <= z_hi; ++tj) {
            for (int idx = tid; idx < 32 * ND; idx += 384) {
                int wp = idx / ND, ti = idx - wp * ND;
                int w  = (wp << 1) + p;
                outr[(size_t)w * OUTD + tj * ND + ti] = 0.f;
            }
        }
    }

    // ---- A fragments: two h-rows per wave (loop-invariant, loaded once) ----
    v8bf16 afrag[2][8];
    {
        int w_a = ((mt * 16 + n) << 1) + p;
        #pragma unroll
        for (int rr = 0; rr < 2; ++rr) {
            int h = h0 + 4 * hg + 2 * rr;
            const float* arow = A + ((size_t)(b * HH + h) * WW + w_a) * CC;
            #pragma unroll
            for (int kc = 0; kc < 8; ++kc) {
                int c0 = kc * 32 + quad * 8;
                float4 f0 = *(const float4*)(arow + c0);
                float4 f1 = *(const float4*)(arow + c0 + 4);
                v8bf16 af;
                af[0] = (__bf16)f0.x; af[1] = (__bf16)f0.y; af[2] = (__bf16)f0.z; af[3] = (__bf16)f0.w;
                af[4] = (__bf16)f1.x; af[5] = (__bf16)f1.y; af[6] = (__bf16)f1.z; af[7] = (__bf16)f1.w;
                afrag[rr][kc] = af;
            }
        }
    }

    store_lds(0);
    int cur = 0;

    // epilogue: D col = n (-> j'), row = quad*4 + q (-> w' within tile)
    auto epilogue = [&](const v4f& acc0, const v4f& acc1, int h, int tj) {
        float* outr = out + (size_t)(b * HH + h) * WW * OUTD;
        #pragma unroll
        for (int q = 0; q < 4; ++q) {
            int wp = mt * 16 + quad * 4 + q;
            int w  = (wp << 1) + p;
            float* orow = outr + (size_t)w * OUTD + tj * ND;
            int ti0 = 10 + n - wp;
            if ((unsigned)ti0 < 21u) orow[ti0] = acc0[q] * (1.f / 256.f);
            int ti1 = 26 + n - wp;
            if ((unsigned)ti1 < 21u) orow[ti1] = acc1[q] * (1.f / 256.f);
            // out-of-image j => exact zeros
            if (n < 10 - wp)  orow[n]      = 0.f;
            if (n <= wp - 22) orow[20 - n] = 0.f;
        }
    };

    for (int i = i_lo; i <= i_hi; ++i) {
        if (i < i_hi) load_pf(h0 - 20 + 2 * (i + 1));   // prefetch next hb
        __syncthreads();   // buf[cur] writes visible; prior readers of cur^1 done

        const int tj0 = i - 2 * hg;        // rr=0 row; rr=1 row has tj0-1
        if ((unsigned)tj0 <= 21u) {        // at least one of the pair valid
            const __bf16* bbase = &Blds[cur][n * PITCH + quad * 8];
            v4f a00 = {0.f, 0.f, 0.f, 0.f};
            v4f a01 = a00, a10 = a00, a11 = a00;
            #pragma unroll
            for (int kc = 0; kc < 8; ++kc) {
                v8bf16 bf0 = *(const v8bf16*)(bbase + kc * 32);                // j' = n
                v8bf16 bf1 = *(const v8bf16*)(bbase + 16 * PITCH + kc * 32);   // j' = 16+n
                a00 = __builtin_amdgcn_mfma_f32_16x16x32_bf16(afrag[0][kc], bf0, a00, 0, 0, 0);
                a01 = __builtin_amdgcn_mfma_f32_16x16x32_bf16(afrag[0][kc], bf1, a01, 0, 0, 0);
                a10 = __builtin_amdgcn_mfma_f32_16x16x32_bf16(afrag[1][kc], bf0, a10, 0, 0, 0);
                a11 = __builtin_amdgcn_mfma_f32_16x16x32_bf16(afrag[1][kc], bf1, a11, 0, 0, 0);
            }
            if ((unsigned)tj0 <= 20u)       epilogue(a00, a01, h0 + 4 * hg,     tj0);
            const int tj1 = tj0 - 1;
            if ((unsigned)tj1 <= 20u)       epilogue(a10, a11, h0 + 4 * hg + 2, tj1);
        }

        if (i < i_hi) store_lds(cur ^ 1);   // consume pf; other buffer, no race
        cur ^= 1;
    }
}

extern "C" void kernel_launch(void* const* d_in, const int* in_sizes, int n_in,
                              void* d_out, int out_size, void* d_ws, size_t ws_size,
                              hipStream_t stream) {
    const float* A = (const float*)d_in[0];
    const float* B = (const float*)d_in[1];
    float* out = (float*)d_out;
    dim3 grid(16 * 32);
    dim3 block(384);
    corr_mfma_kernel<<<grid, block, 0, stream>>>(A, B, out);
}